// Round 2
// baseline (403.861 us; speedup 1.0000x reference)
//
#include <hip/hip_runtime.h>
#include <cstdint>
#include <cstddef>

typedef unsigned short u16;
typedef unsigned int   u32;

typedef __bf16 bf8   __attribute__((ext_vector_type(8)));
typedef float  f32x4 __attribute__((ext_vector_type(4)));

__device__ __forceinline__ float b2f(u16 v) {
  union { u32 i; float f; } c; c.i = ((u32)v) << 16; return c.f;
}
__device__ __forceinline__ u16 f2b(float f) {
  union { u32 i; float f; } c; c.f = f;
  u32 x = c.i;
  u32 r = (x + 0x7FFFu + ((x >> 16) & 1u)) >> 16;
  return (u16)r;
}

// convert 8 consecutive floats to a bf16x8 fragment (RNE)
__device__ __forceinline__ bf8 cvt8(const float* __restrict__ p) {
  f32x4 lo = *(const f32x4*)p;
  f32x4 hi = *(const f32x4*)(p + 4);
  union { u16 s[8]; bf8 v; } c;
#pragma unroll
  for (int i = 0; i < 4; ++i) { c.s[i] = f2b(lo[i]); c.s[4 + i] = f2b(hi[i]); }
  return c.v;
}

// ---------------- weight transpose+convert: W fp32 [K x 128] -> Bt bf16 [128 x K] ----------------
__global__ void k_transpose_all(const float* __restrict__ Win, const float* __restrict__ Whid,
                                const float* __restrict__ Wz, const float* __restrict__ Wr,
                                const float* __restrict__ Wc,
                                u16* __restrict__ Btin, u16* __restrict__ Bthid,
                                u16* __restrict__ Btz, u16* __restrict__ Btr,
                                u16* __restrict__ Btc) {
  int idx = blockIdx.x * 256 + threadIdx.x;
  if (idx >= 131072) return;
  const float* in; u16* out; int K; int off;
  if (idx < 16384)      { in = Win;  out = Btin;  K = 128; off = idx; }
  else if (idx < 32768) { in = Whid; out = Bthid; K = 128; off = idx - 16384; }
  else if (idx < 65536) { in = Wz;   out = Btz;   K = 256; off = idx - 32768; }
  else if (idx < 98304) { in = Wr;   out = Btr;   K = 256; off = idx - 65536; }
  else                  { in = Wc;   out = Btc;   K = 256; off = idx - 98304; }
  int n = off / K, k = off - n * K;
  out[n * K + k] = f2b(in[k * 128 + n]);
}

// ---------------- degree / CSR build ----------------
__global__ void k_zero(int* __restrict__ p, int n) {
  int i = blockIdx.x * 256 + threadIdx.x; if (i < n) p[i] = 0;
}

__global__ void k_count(const int* __restrict__ dst, int* __restrict__ cnt, int E) {
  int e = blockIdx.x * 256 + threadIdx.x; if (e < E) atomicAdd(&cnt[dst[e]], 1);
}

__global__ void k_dinv(const int* __restrict__ cnt, float* __restrict__ dinv, int N) {
  int i = blockIdx.x * 256 + threadIdx.x;
  if (i < N) dinv[i] = rsqrtf((float)cnt[i] + 1.0f);   // +1 self-loop
}

__global__ __launch_bounds__(256) void k_partial(const int* __restrict__ cnt,
                                                 int* __restrict__ bsum, int n) {
  int i = blockIdx.x * 256 + threadIdx.x;
  int v = (i < n) ? cnt[i] : 0;
  for (int off = 1; off < 64; off <<= 1) v += __shfl_down(v, off, 64);
  __shared__ int ws[4];
  int lane = threadIdx.x & 63, w = threadIdx.x >> 6;
  if (lane == 0) ws[w] = v;
  __syncthreads();
  if (threadIdx.x == 0) bsum[blockIdx.x] = ws[0] + ws[1] + ws[2] + ws[3];
}

__global__ void k_scanb(int* __restrict__ bsum, int nb) {
  __shared__ int sm[256];
  int tid = threadIdx.x;
  int v = (tid < nb) ? bsum[tid] : 0;
  sm[tid] = v; __syncthreads();
  int run = v;
  for (int off = 1; off < 256; off <<= 1) {
    int t = (tid >= off) ? sm[tid - off] : 0;
    __syncthreads();
    run += t; sm[tid] = run;
    __syncthreads();
  }
  if (tid < nb) bsum[tid] = run - v;   // exclusive block offsets
}

__global__ __launch_bounds__(256) void k_scatter(const int* __restrict__ cnt,
                                                 const int* __restrict__ bsum,
                                                 int* __restrict__ row_start,
                                                 int* __restrict__ cursor, int n, int E) {
  int tid = threadIdx.x;
  int i = blockIdx.x * 256 + tid;
  int v = (i < n) ? cnt[i] : 0;
  int lane = tid & 63, w = tid >> 6;
  int run = v;
  for (int off = 1; off < 64; off <<= 1) {
    int t = __shfl_up(run, (unsigned)off, 64);
    if (lane >= off) run += t;
  }
  __shared__ int wsum[4];
  if (lane == 63) wsum[w] = run;
  __syncthreads();
  int woff = 0;
  for (int j = 0; j < w; ++j) woff += wsum[j];
  int excl = woff + run - v;
  if (i < n) { int rs = bsum[blockIdx.x] + excl; row_start[i] = rs; cursor[i] = rs; }
  if (i == 0) row_start[n] = E;
}

__global__ void k_fill(const int* __restrict__ src, const int* __restrict__ dst,
                       int* __restrict__ cursor, int* __restrict__ csr_src, int E) {
  int e = blockIdx.x * 256 + threadIdx.x;
  if (e < E) { int p = atomicAdd(&cursor[dst[e]], 1); csr_src[p] = src[e]; }
}

// ---------------- aggregation: one wave per node (y bf16, fp32 accumulate) ----------------
// out[d] = postproc( dinv[d] * (sum_{s->d} y[s] + y[d]) + bias )
__global__ __launch_bounds__(256) void k_agg(const u16* __restrict__ y,
                                             const int* __restrict__ row_start,
                                             const int* __restrict__ csr_src,
                                             const float* __restrict__ dinv,
                                             const float* __restrict__ bias,
                                             u16* __restrict__ out, int relu, int N) {
  int wv = (blockIdx.x * 256 + threadIdx.x) >> 6;
  int lane = threadIdx.x & 63;
  if (wv >= N) return;
  const u32* yr = (const u32*)y;            // 2 bf16 per u32: feats 2*lane, 2*lane+1
  u32 sv = yr[(size_t)wv * 64 + lane];
  float a0 = b2f((u16)(sv & 0xFFFF));
  float a1 = b2f((u16)(sv >> 16));
  int p0 = row_start[wv], p1 = row_start[wv + 1];
  for (int p = p0; p < p1; ++p) {
    int s = csr_src[p];
    u32 v = yr[(size_t)s * 64 + lane];
    a0 += b2f((u16)(v & 0xFFFF));
    a1 += b2f((u16)(v >> 16));
  }
  float di = dinv[wv];
  float r0 = di * a0 + bias[lane * 2];
  float r1 = di * a1 + bias[lane * 2 + 1];
  if (relu) { r0 = fmaxf(r0, 0.0f); r1 = fmaxf(r1, 0.0f); }
  u32 o = (u32)f2b(r0) | ((u32)f2b(r1) << 16);
  ((u32*)out)[(size_t)wv * 64 + lane] = o;
}

// ---------------- GEMM: C[M,128] = [A0|A1][M,K] @ B[K,128], fused epilogues ----------------
// A halves may be fp32 (converted in-register) or bf16. Accumulate fp32 via MFMA.
// MODE 0: outb = bf16(acc * rowscale[row])                      (GCN y = xw*dinv)
// MODE 1: outf = sigmoid(acc + bias)                            (update gate u, fp32)
// MODE 2: outb = bf16(sigmoid(acc + bias) * mulrow[row,col])    (r*h)
// MODE 3: outf = (1-u)*h + u*tanh(acc + bias)                   (final output, fp32)
template <int K, int MODE, bool A0F, bool A1F>
__global__ __launch_bounds__(256) void k_gemm(
    const void* __restrict__ A0v, const void* __restrict__ A1v,
    const u16* __restrict__ Bt,          // [128 x K] bf16 pre-transposed
    const float* __restrict__ rowscale,
    const float* __restrict__ bias,
    const float* __restrict__ mulrow,
    const float* __restrict__ ubuf,
    const float* __restrict__ hbuf,
    u16* __restrict__ outb, float* __restrict__ outf, int M) {
  __shared__ __align__(16) u16 bs[128 * 136];   // 128 cols x (128+8) k, padded
  int tid = threadIdx.x;
  int lane = tid & 63, wave = tid >> 6;
  int ln = lane & 15, quad = lane >> 4;
  int rowbase = blockIdx.x * 64 + wave * 16;
  int rowA = rowbase + ln;
  long rA = (rowA < M) ? rowA : (M - 1);

  f32x4 acc[8];
#pragma unroll
  for (int c = 0; c < 8; ++c) { acc[c][0] = 0.f; acc[c][1] = 0.f; acc[c][2] = 0.f; acc[c][3] = 0.f; }

#pragma unroll
  for (int hh = 0; hh < K / 128; ++hh) {
    if (hh) __syncthreads();
    for (int idx = tid; idx < 128 * 16; idx += 256) {
      int nrow = idx >> 4;
      int kc = (idx & 15) * 8;
      *(bf8*)(bs + nrow * 136 + kc) = *(const bf8*)(Bt + nrow * K + hh * 128 + kc);
    }
    __syncthreads();
    const void* Asrc = (hh == 0) ? A0v : A1v;
    const bool AF = (hh == 0) ? A0F : A1F;
#pragma unroll
    for (int ks = 0; ks < 4; ++ks) {
      int kk = ks * 32 + quad * 8;
      bf8 af;
      if (AF) af = cvt8((const float*)Asrc + rA * 128 + kk);
      else    af = *(const bf8*)((const u16*)Asrc + rA * 128 + kk);
#pragma unroll
      for (int c = 0; c < 8; ++c) {
        bf8 bfr = *(const bf8*)(bs + (c * 16 + ln) * 136 + kk);
        acc[c] = __builtin_amdgcn_mfma_f32_16x16x32_bf16(af, bfr, acc[c], 0, 0, 0);
      }
    }
  }

  int rb = rowbase + quad * 4;
#pragma unroll
  for (int c = 0; c < 8; ++c) {
    int col = c * 16 + ln;
#pragma unroll
    for (int r = 0; r < 4; ++r) {
      int row = rb + r;
      if (row < M) {
        float v = acc[c][r];
        size_t off = (size_t)row * 128 + col;
        if (MODE == 0) {
          outb[off] = f2b(v * rowscale[row]);
        } else if (MODE == 1) {
          v += bias[col];
          outf[off] = 1.0f / (1.0f + expf(-v));
        } else if (MODE == 2) {
          v += bias[col];
          float s = 1.0f / (1.0f + expf(-v));
          outb[off] = f2b(s * mulrow[off]);
        } else {
          v += bias[col];
          float cd = tanhf(v);
          float uu = ubuf[off];
          float hv = hbuf[off];
          outf[off] = (1.0f - uu) * hv + uu * cd;
        }
      }
    }
  }
}

extern "C" void kernel_launch(void* const* d_in, const int* in_sizes, int n_in,
                              void* d_out, int out_size, void* d_ws, size_t ws_size,
                              hipStream_t stream) {
  const float* x     = (const float*)d_in[0];
  const float* h     = (const float*)d_in[1];
  const int*   ei    = (const int*)d_in[2];
  const float* W_in  = (const float*)d_in[3];
  const float* b_in  = (const float*)d_in[4];
  const float* W_hid = (const float*)d_in[5];
  const float* b_hid = (const float*)d_in[6];
  const float* W_z   = (const float*)d_in[7];
  const float* b_z   = (const float*)d_in[8];
  const float* W_r   = (const float*)d_in[9];
  const float* b_r   = (const float*)d_in[10];
  const float* W_c   = (const float*)d_in[11];
  const float* b_c   = (const float*)d_in[12];

  const int N = in_sizes[0] / 128;
  const int E = in_sizes[2] / 2;
  const int* src = ei;
  const int* dst = ei + E;

  char* p = (char*)d_ws;
  auto carve = [&](size_t bytes) { char* r = p; p += (bytes + 255) & ~(size_t)255; return r; };
  u16* Bt_in   = (u16*)carve((size_t)16384 * 2);
  u16* Bt_hid  = (u16*)carve((size_t)16384 * 2);
  u16* Bt_z    = (u16*)carve((size_t)32768 * 2);
  u16* Bt_r    = (u16*)carve((size_t)32768 * 2);
  u16* Bt_c    = (u16*)carve((size_t)32768 * 2);
  int* cnt       = (int*)carve((size_t)N * 4);
  int* row_start = (int*)carve((size_t)(N + 1) * 4);
  int* cursor    = (int*)carve((size_t)N * 4);
  int* bsum      = (int*)carve(1024);
  int* csr       = (int*)carve((size_t)E * 4);
  float* dinv    = (float*)carve((size_t)N * 4);
  u16* y    = (u16*)carve((size_t)N * 128 * 2);    // bf16 intermediates
  u16* h1   = (u16*)carve((size_t)N * 128 * 2);
  u16* emb  = (u16*)carve((size_t)N * 128 * 2);
  u16* rh   = (u16*)carve((size_t)N * 128 * 2);
  float* u  = (float*)carve((size_t)N * 128 * 4);  // update gate fp32

  int gN = (N + 255) / 256;
  int gE = (E + 255) / 256;
  int nb = gN;                 // partial-sum blocks (must be <= 256; 196 here)
  int gG = (N + 63) / 64;      // GEMM: 64 rows per block
  int gA = (N + 3) / 4;        // AGG: 4 waves (nodes) per block

  k_transpose_all<<<512, 256, 0, stream>>>(W_in, W_hid, W_z, W_r, W_c,
                                           Bt_in, Bt_hid, Bt_z, Bt_r, Bt_c);
  k_zero<<<gN, 256, 0, stream>>>(cnt, N);
  k_count<<<gE, 256, 0, stream>>>(dst, cnt, E);
  k_dinv<<<gN, 256, 0, stream>>>(cnt, dinv, N);
  k_partial<<<nb, 256, 0, stream>>>(cnt, bsum, N);
  k_scanb<<<1, 256, 0, stream>>>(bsum, nb);
  k_scatter<<<nb, 256, 0, stream>>>(cnt, bsum, row_start, cursor, N, E);
  k_fill<<<gE, 256, 0, stream>>>(src, dst, cursor, csr, E);

  // layer 1: y = (x @ W_in) * dinv ; h1 = relu(dinv * agg(y) + b_in)
  k_gemm<128, 0, true, false><<<gG, 256, 0, stream>>>(x, nullptr, Bt_in, dinv, nullptr, nullptr, nullptr, nullptr, y, nullptr, N);
  k_agg<<<gA, 256, 0, stream>>>(y, row_start, csr, dinv, b_in, h1, 1, N);
  // layer 2: y = (h1 @ W_hid) * dinv ; emb = dinv * agg(y) + b_hid
  k_gemm<128, 0, false, false><<<gG, 256, 0, stream>>>(h1, nullptr, Bt_hid, dinv, nullptr, nullptr, nullptr, nullptr, y, nullptr, N);
  k_agg<<<gA, 256, 0, stream>>>(y, row_start, csr, dinv, b_hid, emb, 0, N);
  // GRU gates
  k_gemm<256, 1, false, true><<<gG, 256, 0, stream>>>(emb, h, Bt_z, nullptr, b_z, nullptr, nullptr, nullptr, nullptr, u, N);
  k_gemm<256, 2, false, true><<<gG, 256, 0, stream>>>(emb, h, Bt_r, nullptr, b_r, h, nullptr, nullptr, rh, nullptr, N);
  k_gemm<256, 3, false, false><<<gG, 256, 0, stream>>>(emb, rh, Bt_c, nullptr, b_c, nullptr, u, h, nullptr, (float*)d_out, N);
}

// Round 3
// 338.108 us; speedup vs baseline: 1.1945x; 1.1945x over previous
//
#include <hip/hip_runtime.h>
#include <cstdint>
#include <cstddef>

typedef unsigned short u16;
typedef unsigned int   u32;

typedef __bf16 bf8   __attribute__((ext_vector_type(8)));
typedef float  f32x4 __attribute__((ext_vector_type(4)));

__device__ __forceinline__ float b2f(u16 v) {
  union { u32 i; float f; } c; c.i = ((u32)v) << 16; return c.f;
}
__device__ __forceinline__ u16 f2b(float f) {
  union { u32 i; float f; } c; c.f = f;
  u32 x = c.i;
  u32 r = (x + 0x7FFFu + ((x >> 16) & 1u)) >> 16;
  return (u16)r;
}
__device__ __forceinline__ float sigf(float x) { return 1.0f / (1.0f + __expf(-x)); }
__device__ __forceinline__ float tanhfast(float x) { return 2.0f * sigf(2.0f * x) - 1.0f; }

// convert 8 consecutive floats to a bf16x8 fragment (RNE)
__device__ __forceinline__ bf8 cvt8(const float* __restrict__ p) {
  f32x4 lo = *(const f32x4*)p;
  f32x4 hi = *(const f32x4*)(p + 4);
  union { u16 s[8]; bf8 v; } c;
#pragma unroll
  for (int i = 0; i < 4; ++i) { c.s[i] = f2b(lo[i]); c.s[4 + i] = f2b(hi[i]); }
  return c.v;
}

// ---------------- tiled transpose+convert: W fp32 [K x 128] -> Bt bf16 [128 x K] ----------------
__global__ __launch_bounds__(256) void k_transpose(
    const float* __restrict__ W0, const float* __restrict__ W1,
    const float* __restrict__ W2, const float* __restrict__ W3,
    const float* __restrict__ W4,
    u16* __restrict__ B0, u16* __restrict__ B1, u16* __restrict__ B2,
    u16* __restrict__ B3, u16* __restrict__ B4) {
  __shared__ float t[64][65];
  int w = blockIdx.y;
  const float* in; u16* out; int K;
  if (w == 0)      { in = W0; out = B0; K = 128; }
  else if (w == 1) { in = W1; out = B1; K = 128; }
  else if (w == 2) { in = W2; out = B2; K = 256; }
  else if (w == 3) { in = W3; out = B3; K = 256; }
  else             { in = W4; out = B4; K = 256; }
  int ntr = K / 64;                 // tiles along K
  int tidb = blockIdx.x;
  if (tidb >= ntr * 2) return;
  int r0 = (tidb / 2) * 64, c0 = (tidb % 2) * 64;
  int lc = threadIdx.x & 63, lr0 = threadIdx.x >> 6;
#pragma unroll
  for (int i = 0; i < 16; ++i) {
    int lr = lr0 + i * 4;
    t[lr][lc] = in[(size_t)(r0 + lr) * 128 + c0 + lc];
  }
  __syncthreads();
#pragma unroll
  for (int i = 0; i < 16; ++i) {
    int lr = lr0 + i * 4;
    out[(size_t)(c0 + lr) * K + r0 + lc] = f2b(t[lc][lr]);
  }
}

// ---------------- degree / CSR build ----------------
__global__ void k_zero(int* __restrict__ p, int n) {
  int i = blockIdx.x * 256 + threadIdx.x; if (i < n) p[i] = 0;
}

__global__ void k_count(const int* __restrict__ dst, int* __restrict__ cnt, int E) {
  int e = blockIdx.x * 256 + threadIdx.x; if (e < E) atomicAdd(&cnt[dst[e]], 1);
}

__global__ __launch_bounds__(256) void k_partial(const int* __restrict__ cnt,
                                                 int* __restrict__ bsum, int n) {
  int i = blockIdx.x * 256 + threadIdx.x;
  int v = (i < n) ? cnt[i] : 0;
  for (int off = 1; off < 64; off <<= 1) v += __shfl_down(v, off, 64);
  __shared__ int ws[4];
  int lane = threadIdx.x & 63, w = threadIdx.x >> 6;
  if (lane == 0) ws[w] = v;
  __syncthreads();
  if (threadIdx.x == 0) bsum[blockIdx.x] = ws[0] + ws[1] + ws[2] + ws[3];
}

__global__ void k_scanb(int* __restrict__ bsum, int nb) {
  __shared__ int sm[256];
  int tid = threadIdx.x;
  int v = (tid < nb) ? bsum[tid] : 0;
  sm[tid] = v; __syncthreads();
  int run = v;
  for (int off = 1; off < 256; off <<= 1) {
    int t = (tid >= off) ? sm[tid - off] : 0;
    __syncthreads();
    run += t; sm[tid] = run;
    __syncthreads();
  }
  if (tid < nb) bsum[tid] = run - v;   // exclusive block offsets
}

__global__ __launch_bounds__(256) void k_scatter(const int* __restrict__ cnt,
                                                 const int* __restrict__ bsum,
                                                 int* __restrict__ row_start,
                                                 int* __restrict__ cursor,
                                                 float* __restrict__ dinv, int n, int E) {
  int tid = threadIdx.x;
  int i = blockIdx.x * 256 + tid;
  int v = (i < n) ? cnt[i] : 0;
  int lane = tid & 63, w = tid >> 6;
  int run = v;
  for (int off = 1; off < 64; off <<= 1) {
    int t = __shfl_up(run, (unsigned)off, 64);
    if (lane >= off) run += t;
  }
  __shared__ int wsum[4];
  if (lane == 63) wsum[w] = run;
  __syncthreads();
  int woff = 0;
  for (int j = 0; j < w; ++j) woff += wsum[j];
  int excl = woff + run - v;
  if (i < n) {
    int rs = bsum[blockIdx.x] + excl;
    row_start[i] = rs; cursor[i] = rs;
    dinv[i] = rsqrtf((float)v + 1.0f);     // +1 self-loop
  }
  if (i == 0) row_start[n] = E;
}

__global__ void k_fill(const int* __restrict__ src, const int* __restrict__ dst,
                       int* __restrict__ cursor, int* __restrict__ csr_src, int E) {
  int e = blockIdx.x * 256 + threadIdx.x;
  if (e < E) { int p = atomicAdd(&cursor[dst[e]], 1); csr_src[p] = src[e]; }
}

// ---------------- aggregation: one wave per node, batched gathers ----------------
// out[d] = postproc( dinv[d] * (sum_{s->d} y[s] + y[d]) + bias )
__global__ __launch_bounds__(256) void k_agg(const u16* __restrict__ y,
                                             const int* __restrict__ row_start,
                                             const int* __restrict__ csr_src,
                                             const float* __restrict__ dinv,
                                             const float* __restrict__ bias,
                                             u16* __restrict__ out, int relu, int N) {
  int wv = (blockIdx.x * 256 + threadIdx.x) >> 6;
  int lane = threadIdx.x & 63;
  if (wv >= N) return;
  const u32* yr = (const u32*)y;            // 2 bf16 per u32: feats 2*lane, 2*lane+1
  float di = dinv[wv];
  float bi0 = bias[lane * 2], bi1 = bias[lane * 2 + 1];
  u32 sv = yr[(size_t)wv * 64 + lane];
  float a0 = b2f((u16)(sv & 0xFFFF));
  float a1 = b2f((u16)(sv >> 16));
  int p0 = row_start[wv], p1 = row_start[wv + 1];
  int p = p0;
  while (p + 8 <= p1) {
    int s[8]; u32 v[8];
#pragma unroll
    for (int j = 0; j < 8; ++j) s[j] = csr_src[p + j];
#pragma unroll
    for (int j = 0; j < 8; ++j) v[j] = yr[(size_t)s[j] * 64 + lane];
#pragma unroll
    for (int j = 0; j < 8; ++j) { a0 += b2f((u16)(v[j] & 0xFFFF)); a1 += b2f((u16)(v[j] >> 16)); }
    p += 8;
  }
  if (p + 4 <= p1) {
    int s[4]; u32 v[4];
#pragma unroll
    for (int j = 0; j < 4; ++j) s[j] = csr_src[p + j];
#pragma unroll
    for (int j = 0; j < 4; ++j) v[j] = yr[(size_t)s[j] * 64 + lane];
#pragma unroll
    for (int j = 0; j < 4; ++j) { a0 += b2f((u16)(v[j] & 0xFFFF)); a1 += b2f((u16)(v[j] >> 16)); }
    p += 4;
  }
  while (p < p1) {
    int s = csr_src[p++];
    u32 v = yr[(size_t)s * 64 + lane];
    a0 += b2f((u16)(v & 0xFFFF));
    a1 += b2f((u16)(v >> 16));
  }
  float r0 = di * a0 + bi0;
  float r1 = di * a1 + bi1;
  if (relu) { r0 = fmaxf(r0, 0.0f); r1 = fmaxf(r1, 0.0f); }
  u32 o = (u32)f2b(r0) | ((u32)f2b(r1) << 16);
  ((u32*)out)[(size_t)wv * 64 + lane] = o;
}

// ---------------- layer GEMM: y[M,128] = bf16( (A[M,128] @ B) * dinv[row] ) ----------------
template <bool AF>   // A is fp32 (convert) or bf16
__global__ __launch_bounds__(256) void k_gemm(
    const void* __restrict__ Av,
    const u16* __restrict__ Bt,          // [128 x 128] bf16 pre-transposed
    const float* __restrict__ rowscale,
    u16* __restrict__ outb, int M) {
  __shared__ __align__(16) u16 bs[128 * 136];
  int tid = threadIdx.x;
  int lane = tid & 63, wave = tid >> 6;
  int ln = lane & 15, quad = lane >> 4;
  int rowbase = blockIdx.x * 64 + wave * 16;
  int rowA = rowbase + ln;
  long rA = (rowA < M) ? rowA : (M - 1);

  f32x4 acc[8];
#pragma unroll
  for (int c = 0; c < 8; ++c) { acc[c][0] = 0.f; acc[c][1] = 0.f; acc[c][2] = 0.f; acc[c][3] = 0.f; }

  for (int idx = tid; idx < 128 * 16; idx += 256) {
    int nrow = idx >> 4;
    int kc = (idx & 15) * 8;
    *(bf8*)(bs + nrow * 136 + kc) = *(const bf8*)(Bt + nrow * 128 + kc);
  }
  __syncthreads();
#pragma unroll
  for (int ks = 0; ks < 4; ++ks) {
    int kk = ks * 32 + quad * 8;
    bf8 af;
    if (AF) af = cvt8((const float*)Av + rA * 128 + kk);
    else    af = *(const bf8*)((const u16*)Av + rA * 128 + kk);
#pragma unroll
    for (int c = 0; c < 8; ++c) {
      bf8 bfr = *(const bf8*)(bs + (c * 16 + ln) * 136 + kk);
      acc[c] = __builtin_amdgcn_mfma_f32_16x16x32_bf16(af, bfr, acc[c], 0, 0, 0);
    }
  }

  int rb = rowbase + quad * 4;
#pragma unroll
  for (int c = 0; c < 8; ++c) {
    int col = c * 16 + ln;
#pragma unroll
    for (int r = 0; r < 4; ++r) {
      int row = rb + r;
      if (row < M) outb[(size_t)row * 128 + col] = f2b(acc[c][r] * rowscale[row]);
    }
  }
}

// ---------------- fused GRU: out = (1-u)*h + u*tanh([emb | sig(r)*h] @ Wc + bc) ----------------
__global__ __launch_bounds__(256) void k_gru(
    const u16* __restrict__ emb, const float* __restrict__ h,
    const u16* __restrict__ Btz, const u16* __restrict__ Btr, const u16* __restrict__ Btc,
    const float* __restrict__ bz, const float* __restrict__ br, const float* __restrict__ bc,
    float* __restrict__ out, int M) {
  __shared__ __align__(16) u16 bs[128 * 136];   // weight K-half tile
  __shared__ __align__(16) u16 at[64 * 136];    // rh A-tile (block rows)
  int tid = threadIdx.x;
  int lane = tid & 63, wave = tid >> 6;
  int ln = lane & 15, quad = lane >> 4;
  int rowbase = blockIdx.x * 64 + wave * 16;
  int rowA = rowbase + ln;
  long rA = (rowA < M) ? rowA : (M - 1);

  // cache A fragments for both K-halves: emb (bf16), h (fp32 -> bf16)
  bf8 af_e[4], af_h[4];
#pragma unroll
  for (int ks = 0; ks < 4; ++ks) {
    int kk = ks * 32 + quad * 8;
    af_e[ks] = *(const bf8*)(emb + rA * 128 + kk);
    af_h[ks] = cvt8(h + rA * 128 + kk);
  }

  f32x4 accz[8], accr[8];
#pragma unroll
  for (int c = 0; c < 8; ++c) {
    accz[c][0] = 0.f; accz[c][1] = 0.f; accz[c][2] = 0.f; accz[c][3] = 0.f;
    accr[c][0] = 0.f; accr[c][1] = 0.f; accr[c][2] = 0.f; accr[c][3] = 0.f;
  }

  auto stage = [&](const u16* Bt, int hh) {
    for (int idx = tid; idx < 128 * 16; idx += 256) {
      int nrow = idx >> 4;
      int kc = (idx & 15) * 8;
      *(bf8*)(bs + nrow * 136 + kc) = *(const bf8*)(Bt + nrow * 256 + hh * 128 + kc);
    }
  };
  auto mm = [&](f32x4 (&acc)[8], const bf8 (&af)[4]) {
#pragma unroll
    for (int ks = 0; ks < 4; ++ks) {
      int kk = ks * 32 + quad * 8;
#pragma unroll
      for (int c = 0; c < 8; ++c) {
        bf8 bfr = *(const bf8*)(bs + (c * 16 + ln) * 136 + kk);
        acc[c] = __builtin_amdgcn_mfma_f32_16x16x32_bf16(af[ks], bfr, acc[c], 0, 0, 0);
      }
    }
  };

  stage(Btz, 0); __syncthreads(); mm(accz, af_e);
  __syncthreads(); stage(Btz, 1); __syncthreads(); mm(accz, af_h);
  __syncthreads(); stage(Btr, 0); __syncthreads(); mm(accr, af_e);
  __syncthreads(); stage(Btr, 1); __syncthreads(); mm(accr, af_h);

  // h at C-layout positions (cached for rh and final blend)
  int rb = rowbase + quad * 4;
  f32x4 hc[8];
#pragma unroll
  for (int c = 0; c < 8; ++c) {
    int col = c * 16 + ln;
#pragma unroll
    for (int r = 0; r < 4; ++r) {
      int row = rb + r;
      hc[c][r] = (row < M) ? h[(size_t)row * 128 + col] : 0.0f;
    }
  }

  // u = sigmoid(accz+bz); r = sigmoid(accr+br); rh -> LDS A-tile (bf16)
#pragma unroll
  for (int c = 0; c < 8; ++c) {
    int col = c * 16 + ln;
    float bzc = bz[col], brc = br[col];
#pragma unroll
    for (int r = 0; r < 4; ++r) {
      float uu = sigf(accz[c][r] + bzc);
      float rr = sigf(accr[c][r] + brc);
      accz[c][r] = uu;                       // keep u in registers
      int lrow = wave * 16 + quad * 4 + r;   // local block row
      at[lrow * 136 + col] = f2b(rr * hc[c][r]);
      accr[c][r] = 0.0f;                     // reuse accr as candidate accumulator
    }
  }

  __syncthreads();                            // all waves done with bs + at written
  stage(Btc, 0); __syncthreads(); mm(accr, af_e);
  __syncthreads(); stage(Btc, 1); __syncthreads();
  {
    bf8 af[4];
#pragma unroll
    for (int ks = 0; ks < 4; ++ks) {
      int kk = ks * 32 + quad * 8;
      af[ks] = *(const bf8*)(at + (wave * 16 + ln) * 136 + kk);
    }
    mm(accr, af);
  }

  // epilogue: out = (1-u)*h + u*tanh(accc + bc)
#pragma unroll
  for (int c = 0; c < 8; ++c) {
    int col = c * 16 + ln;
    float bcc = bc[col];
#pragma unroll
    for (int r = 0; r < 4; ++r) {
      int row = rb + r;
      if (row < M) {
        float cd = tanhfast(accr[c][r] + bcc);
        float uu = accz[c][r];
        out[(size_t)row * 128 + col] = (1.0f - uu) * hc[c][r] + uu * cd;
      }
    }
  }
}

extern "C" void kernel_launch(void* const* d_in, const int* in_sizes, int n_in,
                              void* d_out, int out_size, void* d_ws, size_t ws_size,
                              hipStream_t stream) {
  const float* x     = (const float*)d_in[0];
  const float* h     = (const float*)d_in[1];
  const int*   ei    = (const int*)d_in[2];
  const float* W_in  = (const float*)d_in[3];
  const float* b_in  = (const float*)d_in[4];
  const float* W_hid = (const float*)d_in[5];
  const float* b_hid = (const float*)d_in[6];
  const float* W_z   = (const float*)d_in[7];
  const float* b_z   = (const float*)d_in[8];
  const float* W_r   = (const float*)d_in[9];
  const float* b_r   = (const float*)d_in[10];
  const float* W_c   = (const float*)d_in[11];
  const float* b_c   = (const float*)d_in[12];

  const int N = in_sizes[0] / 128;
  const int E = in_sizes[2] / 2;
  const int* src = ei;
  const int* dst = ei + E;

  char* p = (char*)d_ws;
  auto carve = [&](size_t bytes) { char* r = p; p += (bytes + 255) & ~(size_t)255; return r; };
  u16* Bt_in   = (u16*)carve((size_t)16384 * 2);
  u16* Bt_hid  = (u16*)carve((size_t)16384 * 2);
  u16* Bt_z    = (u16*)carve((size_t)32768 * 2);
  u16* Bt_r    = (u16*)carve((size_t)32768 * 2);
  u16* Bt_c    = (u16*)carve((size_t)32768 * 2);
  int* cnt       = (int*)carve((size_t)N * 4);
  int* row_start = (int*)carve((size_t)(N + 1) * 4);
  int* cursor    = (int*)carve((size_t)N * 4);
  int* bsum      = (int*)carve(1024);
  int* csr       = (int*)carve((size_t)E * 4);
  float* dinv    = (float*)carve((size_t)N * 4);
  u16* y    = (u16*)carve((size_t)N * 128 * 2);    // bf16 intermediates
  u16* h1   = (u16*)carve((size_t)N * 128 * 2);
  u16* emb  = (u16*)carve((size_t)N * 128 * 2);

  int gN = (N + 255) / 256;
  int gE = (E + 255) / 256;
  int nb = gN;                 // partial-sum blocks (<=256; 196 here)
  int gG = (N + 63) / 64;      // GEMM/GRU: 64 rows per block
  int gA = (N + 3) / 4;        // AGG: 4 waves (nodes) per block

  k_transpose<<<dim3(8, 5), 256, 0, stream>>>(W_in, W_hid, W_z, W_r, W_c,
                                              Bt_in, Bt_hid, Bt_z, Bt_r, Bt_c);
  k_zero<<<gN, 256, 0, stream>>>(cnt, N);
  k_count<<<gE, 256, 0, stream>>>(dst, cnt, E);
  k_partial<<<nb, 256, 0, stream>>>(cnt, bsum, N);
  k_scanb<<<1, 256, 0, stream>>>(bsum, nb);
  k_scatter<<<nb, 256, 0, stream>>>(cnt, bsum, row_start, cursor, dinv, N, E);
  k_fill<<<gE, 256, 0, stream>>>(src, dst, cursor, csr, E);

  // layer 1: y = (x @ W_in) * dinv ; h1 = relu(dinv * agg(y) + b_in)
  k_gemm<true><<<gG, 256, 0, stream>>>(x, Bt_in, dinv, y, N);
  k_agg<<<gA, 256, 0, stream>>>(y, row_start, csr, dinv, b_in, h1, 1, N);
  // layer 2: y = (h1 @ W_hid) * dinv ; emb = dinv * agg(y) + b_hid
  k_gemm<false><<<gG, 256, 0, stream>>>(h1, Bt_hid, dinv, y, N);
  k_agg<<<gA, 256, 0, stream>>>(y, row_start, csr, dinv, b_hid, emb, 0, N);
  // fused GRU
  k_gru<<<gG, 256, 0, stream>>>(emb, h, Bt_z, Bt_r, Bt_c, b_z, b_r, b_c, (float*)d_out, N);
}

// Round 4
// 302.235 us; speedup vs baseline: 1.3362x; 1.1187x over previous
//
#include <hip/hip_runtime.h>
#include <cstdint>
#include <cstddef>

typedef unsigned short u16;
typedef unsigned int   u32;

typedef __bf16 bf8   __attribute__((ext_vector_type(8)));
typedef float  f32x4 __attribute__((ext_vector_type(4)));

__device__ __forceinline__ float b2f(u16 v) {
  union { u32 i; float f; } c; c.i = ((u32)v) << 16; return c.f;
}
__device__ __forceinline__ u16 f2b(float f) {
  union { u32 i; float f; } c; c.f = f;
  u32 x = c.i;
  u32 r = (x + 0x7FFFu + ((x >> 16) & 1u)) >> 16;
  return (u16)r;
}
__device__ __forceinline__ float sigf(float x) { return 1.0f / (1.0f + __expf(-x)); }
__device__ __forceinline__ float tanhfast(float x) { return 2.0f * sigf(2.0f * x) - 1.0f; }

// convert 8 consecutive floats to a bf16x8 fragment (RNE)
__device__ __forceinline__ bf8 cvt8(const float* __restrict__ p) {
  f32x4 lo = *(const f32x4*)p;
  f32x4 hi = *(const f32x4*)(p + 4);
  union { u16 s[8]; bf8 v; } c;
#pragma unroll
  for (int i = 0; i < 4; ++i) { c.s[i] = f2b(lo[i]); c.s[4 + i] = f2b(hi[i]); }
  return c.v;
}

// async 16B global -> LDS (dest = wave-uniform base + lane*16)
__device__ __forceinline__ void ld_lds16(const u16* g, u16* l) {
  __builtin_amdgcn_global_load_lds((const __attribute__((address_space(1))) void*)g,
                                   (__attribute__((address_space(3))) void*)l, 16, 0, 0);
}

// ---- weight repack: W fp32 [K x 128] -> Bt bf16 in MFMA-fragment order ----
// frag id f = hh*2048 + ks*512 + c*64 + quad*16 + ln ; element j in [0,8):
//   Bt[f*8+j] = bf16( W[(hh*128+ks*32+quad*8+j)*128 + (c*16+ln)] )
__global__ __launch_bounds__(256) void k_transpose(
    const float* __restrict__ W0, const float* __restrict__ W1,
    const float* __restrict__ W2, const float* __restrict__ W3,
    const float* __restrict__ W4,
    u16* __restrict__ B0, u16* __restrict__ B1, u16* __restrict__ B2,
    u16* __restrict__ B3, u16* __restrict__ B4) {
  int t = blockIdx.x * 256 + threadIdx.x;
  if (t >= 16384) return;
  const float* in; u16* out; int f;
  if (t < 2048)       { in = W0; out = B0; f = t; }
  else if (t < 4096)  { in = W1; out = B1; f = t - 2048; }
  else if (t < 8192)  { in = W2; out = B2; f = t - 4096; }
  else if (t < 12288) { in = W3; out = B3; f = t - 8192; }
  else                { in = W4; out = B4; f = t - 12288; }
  int ln = f & 15, quad = (f >> 4) & 3, c = (f >> 6) & 7, ks = (f >> 9) & 3, hh = f >> 11;
  int n = c * 16 + ln;
  int k0 = hh * 128 + ks * 32 + quad * 8;
  union { u16 s[8]; uint4 q; } tmp;
#pragma unroll
  for (int j = 0; j < 8; ++j) tmp.s[j] = f2b(in[(size_t)(k0 + j) * 128 + n]);
  *(uint4*)(out + (size_t)f * 8) = tmp.q;
}

// ---------------- degree / CSR build ----------------
__global__ void k_zero(int* __restrict__ p, int n) {
  int i = blockIdx.x * 256 + threadIdx.x; if (i < n) p[i] = 0;
}

__global__ void k_count(const int* __restrict__ dst, int* __restrict__ cnt, int E) {
  int e = blockIdx.x * 256 + threadIdx.x; if (e < E) atomicAdd(&cnt[dst[e]], 1);
}

__global__ __launch_bounds__(256) void k_partial(const int* __restrict__ cnt,
                                                 int* __restrict__ bsum, int n) {
  int i = blockIdx.x * 256 + threadIdx.x;
  int v = (i < n) ? cnt[i] : 0;
  for (int off = 1; off < 64; off <<= 1) v += __shfl_down(v, off, 64);
  __shared__ int ws[4];
  int lane = threadIdx.x & 63, w = threadIdx.x >> 6;
  if (lane == 0) ws[w] = v;
  __syncthreads();
  if (threadIdx.x == 0) bsum[blockIdx.x] = ws[0] + ws[1] + ws[2] + ws[3];
}

__global__ void k_scanb(int* __restrict__ bsum, int nb) {
  __shared__ int sm[256];
  int tid = threadIdx.x;
  int v = (tid < nb) ? bsum[tid] : 0;
  sm[tid] = v; __syncthreads();
  int run = v;
  for (int off = 1; off < 256; off <<= 1) {
    int t = (tid >= off) ? sm[tid - off] : 0;
    __syncthreads();
    run += t; sm[tid] = run;
    __syncthreads();
  }
  if (tid < nb) bsum[tid] = run - v;   // exclusive block offsets
}

__global__ __launch_bounds__(256) void k_scatter(const int* __restrict__ cnt,
                                                 const int* __restrict__ bsum,
                                                 int* __restrict__ row_start,
                                                 int* __restrict__ cursor,
                                                 float* __restrict__ dinv, int n, int E) {
  int tid = threadIdx.x;
  int i = blockIdx.x * 256 + tid;
  int v = (i < n) ? cnt[i] : 0;
  int lane = tid & 63, w = tid >> 6;
  int run = v;
  for (int off = 1; off < 64; off <<= 1) {
    int t = __shfl_up(run, (unsigned)off, 64);
    if (lane >= off) run += t;
  }
  __shared__ int wsum[4];
  if (lane == 63) wsum[w] = run;
  __syncthreads();
  int woff = 0;
  for (int j = 0; j < w; ++j) woff += wsum[j];
  int excl = woff + run - v;
  if (i < n) {
    int rs = bsum[blockIdx.x] + excl;
    row_start[i] = rs; cursor[i] = rs;
    dinv[i] = rsqrtf((float)v + 1.0f);     // +1 self-loop
  }
  if (i == 0) row_start[n] = E;
}

__global__ void k_fill(const int* __restrict__ src, const int* __restrict__ dst,
                       int* __restrict__ cursor, int* __restrict__ csr_src, int E) {
  int e = blockIdx.x * 256 + threadIdx.x;
  if (e < E) { int p = atomicAdd(&cursor[dst[e]], 1); csr_src[p] = src[e]; }
}

// ---------------- aggregation: one wave per node, batched gathers ----------------
__global__ __launch_bounds__(256) void k_agg(const u16* __restrict__ y,
                                             const int* __restrict__ row_start,
                                             const int* __restrict__ csr_src,
                                             const float* __restrict__ dinv,
                                             const float* __restrict__ bias,
                                             u16* __restrict__ out, int relu, int N) {
  int wv = (blockIdx.x * 256 + threadIdx.x) >> 6;
  int lane = threadIdx.x & 63;
  if (wv >= N) return;
  const u32* yr = (const u32*)y;            // 2 bf16 per u32: feats 2*lane, 2*lane+1
  float di = dinv[wv];
  float bi0 = bias[lane * 2], bi1 = bias[lane * 2 + 1];
  u32 sv = yr[(size_t)wv * 64 + lane];
  float a0 = b2f((u16)(sv & 0xFFFF));
  float a1 = b2f((u16)(sv >> 16));
  int p0 = row_start[wv], p1 = row_start[wv + 1];
  int p = p0;
  while (p + 8 <= p1) {
    int s[8]; u32 v[8];
#pragma unroll
    for (int j = 0; j < 8; ++j) s[j] = csr_src[p + j];
#pragma unroll
    for (int j = 0; j < 8; ++j) v[j] = yr[(size_t)s[j] * 64 + lane];
#pragma unroll
    for (int j = 0; j < 8; ++j) { a0 += b2f((u16)(v[j] & 0xFFFF)); a1 += b2f((u16)(v[j] >> 16)); }
    p += 8;
  }
  if (p + 4 <= p1) {
    int s[4]; u32 v[4];
#pragma unroll
    for (int j = 0; j < 4; ++j) s[j] = csr_src[p + j];
#pragma unroll
    for (int j = 0; j < 4; ++j) v[j] = yr[(size_t)s[j] * 64 + lane];
#pragma unroll
    for (int j = 0; j < 4; ++j) { a0 += b2f((u16)(v[j] & 0xFFFF)); a1 += b2f((u16)(v[j] >> 16)); }
    p += 4;
  }
  while (p < p1) {
    int s = csr_src[p++];
    u32 v = yr[(size_t)s * 64 + lane];
    a0 += b2f((u16)(v & 0xFFFF));
    a1 += b2f((u16)(v >> 16));
  }
  float r0 = di * a0 + bi0;
  float r1 = di * a1 + bi1;
  if (relu) { r0 = fmaxf(r0, 0.0f); r1 = fmaxf(r1, 0.0f); }
  u32 o = (u32)f2b(r0) | ((u32)f2b(r1) << 16);
  ((u32*)out)[(size_t)wv * 64 + lane] = o;
}

// ---------------- layer GEMM: y[M,128] = bf16( (A[M,128] @ W) * dinv[row] ) ----------------
template <bool AF>   // A is fp32 (convert) or bf16
__global__ __launch_bounds__(256) void k_gemm(
    const void* __restrict__ Av,
    const u16* __restrict__ Bt,          // fragment-ordered, 16384 u16
    const float* __restrict__ rowscale,
    u16* __restrict__ outb, int M) {
  __shared__ __align__(16) u16 bs[16384];
  int tid = threadIdx.x;
  int lane = tid & 63, wave = tid >> 6;
  int ln = lane & 15, quad = lane >> 4;
  int rowbase = blockIdx.x * 64 + wave * 16;
  int rowA = rowbase + ln;
  long rA = (rowA < M) ? rowA : (M - 1);

  {
    const u16* g = Bt + wave * 4096 + lane * 8;
    u16* l = bs + wave * 4096;
#pragma unroll
    for (int i = 0; i < 8; ++i) ld_lds16(g + i * 512, l + i * 512);
  }

  bf8 af[4];
#pragma unroll
  for (int ks = 0; ks < 4; ++ks) {
    int kk = ks * 32 + quad * 8;
    if (AF) af[ks] = cvt8((const float*)Av + rA * 128 + kk);
    else    af[ks] = *(const bf8*)((const u16*)Av + rA * 128 + kk);
  }

  f32x4 acc[8];
#pragma unroll
  for (int c = 0; c < 8; ++c) { acc[c][0] = 0.f; acc[c][1] = 0.f; acc[c][2] = 0.f; acc[c][3] = 0.f; }

  __syncthreads();   // drains the async LDS DMA
#pragma unroll
  for (int ks = 0; ks < 4; ++ks) {
#pragma unroll
    for (int c = 0; c < 8; ++c) {
      bf8 bfr = *(const bf8*)(bs + ks * 4096 + c * 512 + lane * 8);
      acc[c] = __builtin_amdgcn_mfma_f32_16x16x32_bf16(af[ks], bfr, acc[c], 0, 0, 0);
    }
  }

  int rb = rowbase + quad * 4;
#pragma unroll
  for (int c = 0; c < 8; ++c) {
    int col = c * 16 + ln;
#pragma unroll
    for (int r = 0; r < 4; ++r) {
      int row = rb + r;
      if (row < M) outb[(size_t)row * 128 + col] = f2b(acc[c][r] * rowscale[row]);
    }
  }
}

// ---------------- fused GRU: out = (1-u)*h + u*tanh([emb | sig(r)*h] @ Wc + bc) ----------------
__global__ __launch_bounds__(256) void k_gru(
    const u16* __restrict__ emb, const float* __restrict__ h,
    const u16* __restrict__ Btz, const u16* __restrict__ Btr, const u16* __restrict__ Btc,
    const float* __restrict__ bz, const float* __restrict__ br, const float* __restrict__ bc,
    float* __restrict__ out, int M) {
  __shared__ __align__(16) u16 bs[16384];     // one 32KB weight-half buffer
  __shared__ __align__(16) u16 at[64 * 136];  // rh A-tile (padded, ds round-trip)
  int tid = threadIdx.x;
  int lane = tid & 63, wave = tid >> 6;
  int ln = lane & 15, quad = lane >> 4;
  int rowbase = blockIdx.x * 64 + wave * 16;
  int rowA = rowbase + ln;
  long rA = (rowA < M) ? rowA : (M - 1);
  int rb = rowbase + quad * 4;

  auto stage = [&](const u16* Bt, int hh) {
    const u16* g = Bt + hh * 16384 + wave * 4096 + lane * 8;
    u16* l = bs + wave * 4096;
#pragma unroll
    for (int i = 0; i < 8; ++i) ld_lds16(g + i * 512, l + i * 512);
  };
  auto mmE = [&](f32x4 (&acc)[8]) {           // A = emb (bf16)
    bf8 af[4];
#pragma unroll
    for (int ks = 0; ks < 4; ++ks) af[ks] = *(const bf8*)(emb + rA * 128 + ks * 32 + quad * 8);
#pragma unroll
    for (int ks = 0; ks < 4; ++ks)
#pragma unroll
      for (int c = 0; c < 8; ++c) {
        bf8 bfr = *(const bf8*)(bs + ks * 4096 + c * 512 + lane * 8);
        acc[c] = __builtin_amdgcn_mfma_f32_16x16x32_bf16(af[ks], bfr, acc[c], 0, 0, 0);
      }
  };
  auto mmH = [&](f32x4 (&acc)[8]) {           // A = h (fp32 -> bf16)
    bf8 af[4];
#pragma unroll
    for (int ks = 0; ks < 4; ++ks) af[ks] = cvt8(h + rA * 128 + ks * 32 + quad * 8);
#pragma unroll
    for (int ks = 0; ks < 4; ++ks)
#pragma unroll
      for (int c = 0; c < 8; ++c) {
        bf8 bfr = *(const bf8*)(bs + ks * 4096 + c * 512 + lane * 8);
        acc[c] = __builtin_amdgcn_mfma_f32_16x16x32_bf16(af[ks], bfr, acc[c], 0, 0, 0);
      }
  };

  f32x4 accz[8], accr[8];
#pragma unroll
  for (int c = 0; c < 8; ++c) {
    accz[c][0] = 0.f; accz[c][1] = 0.f; accz[c][2] = 0.f; accz[c][3] = 0.f;
    accr[c][0] = 0.f; accr[c][1] = 0.f; accr[c][2] = 0.f; accr[c][3] = 0.f;
  }

  stage(Btz, 0);
  // overlap: preload h at C-layout positions (for rh and final blend)
  f32x4 hc[8];
#pragma unroll
  for (int c = 0; c < 8; ++c) {
    int col = c * 16 + ln;
#pragma unroll
    for (int r = 0; r < 4; ++r) {
      int row = rb + r;
      hc[c][r] = (row < M) ? h[(size_t)row * 128 + col] : 0.0f;
    }
  }
  __syncthreads(); mmE(accz); __syncthreads();
  stage(Btz, 1); __syncthreads(); mmH(accz); __syncthreads();
  stage(Btr, 0); __syncthreads(); mmE(accr); __syncthreads();
  stage(Btr, 1); __syncthreads(); mmH(accr); __syncthreads();

  // u = sigmoid(accz+bz); rh = sigmoid(accr+br)*h -> LDS A-tile (bf16)
#pragma unroll
  for (int c = 0; c < 8; ++c) {
    int col = c * 16 + ln;
    float bzc = bz[col], brc = br[col];
#pragma unroll
    for (int r = 0; r < 4; ++r) {
      float uu = sigf(accz[c][r] + bzc);
      float rr = sigf(accr[c][r] + brc);
      accz[c][r] = uu;                       // keep u in registers
      int lrow = wave * 16 + quad * 4 + r;   // local block row
      at[lrow * 136 + col] = f2b(rr * hc[c][r]);
      accr[c][r] = 0.0f;                     // reuse accr as candidate accumulator
    }
  }
  __syncthreads();                           // at visible to all waves

  stage(Btc, 0); __syncthreads(); mmE(accr); __syncthreads();
  stage(Btc, 1); __syncthreads();
  {
    bf8 af[4];
#pragma unroll
    for (int ks = 0; ks < 4; ++ks)
      af[ks] = *(const bf8*)(at + (wave * 16 + ln) * 136 + ks * 32 + quad * 8);
#pragma unroll
    for (int ks = 0; ks < 4; ++ks)
#pragma unroll
      for (int c = 0; c < 8; ++c) {
        bf8 bfr = *(const bf8*)(bs + ks * 4096 + c * 512 + lane * 8);
        accr[c] = __builtin_amdgcn_mfma_f32_16x16x32_bf16(af[ks], bfr, accr[c], 0, 0, 0);
      }
  }

  // epilogue: out = (1-u)*h + u*tanh(accc + bc)
#pragma unroll
  for (int c = 0; c < 8; ++c) {
    int col = c * 16 + ln;
    float bcc = bc[col];
#pragma unroll
    for (int r = 0; r < 4; ++r) {
      int row = rb + r;
      if (row < M) {
        float cd = tanhfast(accr[c][r] + bcc);
        float uu = accz[c][r];
        out[(size_t)row * 128 + col] = (1.0f - uu) * hc[c][r] + uu * cd;
      }
    }
  }
}

extern "C" void kernel_launch(void* const* d_in, const int* in_sizes, int n_in,
                              void* d_out, int out_size, void* d_ws, size_t ws_size,
                              hipStream_t stream) {
  const float* x     = (const float*)d_in[0];
  const float* h     = (const float*)d_in[1];
  const int*   ei    = (const int*)d_in[2];
  const float* W_in  = (const float*)d_in[3];
  const float* b_in  = (const float*)d_in[4];
  const float* W_hid = (const float*)d_in[5];
  const float* b_hid = (const float*)d_in[6];
  const float* W_z   = (const float*)d_in[7];
  const float* b_z   = (const float*)d_in[8];
  const float* W_r   = (const float*)d_in[9];
  const float* b_r   = (const float*)d_in[10];
  const float* W_c   = (const float*)d_in[11];
  const float* b_c   = (const float*)d_in[12];

  const int N = in_sizes[0] / 128;
  const int E = in_sizes[2] / 2;
  const int* src = ei;
  const int* dst = ei + E;

  char* p = (char*)d_ws;
  auto carve = [&](size_t bytes) { char* r = p; p += (bytes + 255) & ~(size_t)255; return r; };
  u16* Bt_in   = (u16*)carve((size_t)16384 * 2);
  u16* Bt_hid  = (u16*)carve((size_t)16384 * 2);
  u16* Bt_z    = (u16*)carve((size_t)32768 * 2);
  u16* Bt_r    = (u16*)carve((size_t)32768 * 2);
  u16* Bt_c    = (u16*)carve((size_t)32768 * 2);
  int* cnt       = (int*)carve((size_t)N * 4);
  int* row_start = (int*)carve((size_t)(N + 1) * 4);
  int* cursor    = (int*)carve((size_t)N * 4);
  int* bsum      = (int*)carve(1024);
  int* csr       = (int*)carve((size_t)E * 4);
  float* dinv    = (float*)carve((size_t)N * 4);
  u16* y    = (u16*)carve((size_t)N * 128 * 2);    // bf16 intermediates
  u16* h1   = (u16*)carve((size_t)N * 128 * 2);
  u16* emb  = (u16*)carve((size_t)N * 128 * 2);

  int gN = (N + 255) / 256;
  int gE = (E + 255) / 256;
  int nb = gN;                 // partial-sum blocks (<=256; 196 here)
  int gG = (N + 63) / 64;      // GEMM/GRU: 64 rows per block
  int gA = (N + 3) / 4;        // AGG: 4 waves (nodes) per block

  k_transpose<<<64, 256, 0, stream>>>(W_in, W_hid, W_z, W_r, W_c,
                                      Bt_in, Bt_hid, Bt_z, Bt_r, Bt_c);
  k_zero<<<gN, 256, 0, stream>>>(cnt, N);
  k_count<<<gE, 256, 0, stream>>>(dst, cnt, E);
  k_partial<<<nb, 256, 0, stream>>>(cnt, bsum, N);
  k_scanb<<<1, 256, 0, stream>>>(bsum, nb);
  k_scatter<<<nb, 256, 0, stream>>>(cnt, bsum, row_start, cursor, dinv, N, E);
  k_fill<<<gE, 256, 0, stream>>>(src, dst, cursor, csr, E);

  // layer 1: y = (x @ W_in) * dinv ; h1 = relu(dinv * agg(y) + b_in)
  k_gemm<true><<<gG, 256, 0, stream>>>(x, Bt_in, dinv, y, N);
  k_agg<<<gA, 256, 0, stream>>>(y, row_start, csr, dinv, b_in, h1, 1, N);
  // layer 2: y = (h1 @ W_hid) * dinv ; emb = dinv * agg(y) + b_hid
  k_gemm<false><<<gG, 256, 0, stream>>>(h1, Bt_hid, dinv, y, N);
  k_agg<<<gA, 256, 0, stream>>>(y, row_start, csr, dinv, b_hid, emb, 0, N);
  // fused GRU
  k_gru<<<gG, 256, 0, stream>>>(emb, h, Bt_z, Bt_r, Bt_c, b_z, b_r, b_c, (float*)d_out, N);
}

// Round 5
// 298.135 us; speedup vs baseline: 1.3546x; 1.0138x over previous
//
#include <hip/hip_runtime.h>
#include <cstdint>
#include <cstddef>

typedef unsigned short u16;
typedef unsigned int   u32;

typedef __bf16 bf8   __attribute__((ext_vector_type(8)));
typedef float  f32x4 __attribute__((ext_vector_type(4)));

__device__ __forceinline__ float b2f(u16 v) {
  union { u32 i; float f; } c; c.i = ((u32)v) << 16; return c.f;
}
__device__ __forceinline__ u16 f2b(float f) {
  union { u32 i; float f; } c; c.f = f;
  u32 x = c.i;
  u32 r = (x + 0x7FFFu + ((x >> 16) & 1u)) >> 16;
  return (u16)r;
}
__device__ __forceinline__ float sigf(float x) { return 1.0f / (1.0f + __expf(-x)); }
__device__ __forceinline__ float tanhfast(float x) { return 2.0f * sigf(2.0f * x) - 1.0f; }

// convert 8 consecutive floats to a bf16x8 fragment (RNE)
__device__ __forceinline__ bf8 cvt8(const float* __restrict__ p) {
  f32x4 lo = *(const f32x4*)p;
  f32x4 hi = *(const f32x4*)(p + 4);
  union { u16 s[8]; bf8 v; } c;
#pragma unroll
  for (int i = 0; i < 4; ++i) { c.s[i] = f2b(lo[i]); c.s[4 + i] = f2b(hi[i]); }
  return c.v;
}

// async 16B global -> LDS (dest = wave-uniform base + lane*16)
__device__ __forceinline__ void ld_lds16(const u16* g, u16* l) {
  __builtin_amdgcn_global_load_lds((const __attribute__((address_space(1))) void*)g,
                                   (__attribute__((address_space(3))) void*)l, 16, 0, 0);
}

// ---- weight repack: W fp32 [K x 128] -> Bt bf16 in MFMA-fragment order ----
// frag id f = hh*2048 + ks*512 + c*64 + quad*16 + ln ; element j in [0,8):
//   Bt[f*8+j] = bf16( W[(hh*128+ks*32+quad*8+j)*128 + (c*16+ln)] )
// blocks >= 64 zero the degree-count array instead (folded k_zero).
__global__ __launch_bounds__(256) void k_transpose(
    const float* __restrict__ W0, const float* __restrict__ W1,
    const float* __restrict__ W2, const float* __restrict__ W3,
    const float* __restrict__ W4,
    u16* __restrict__ B0, u16* __restrict__ B1, u16* __restrict__ B2,
    u16* __restrict__ B3, u16* __restrict__ B4,
    int* __restrict__ cnt, int N) {
  if (blockIdx.x >= 64) {
    int i = (blockIdx.x - 64) * 256 + threadIdx.x;
    if (i < N) cnt[i] = 0;
    return;
  }
  int t = blockIdx.x * 256 + threadIdx.x;
  const float* in; u16* out; int f;
  if (t < 2048)       { in = W0; out = B0; f = t; }
  else if (t < 4096)  { in = W1; out = B1; f = t - 2048; }
  else if (t < 8192)  { in = W2; out = B2; f = t - 4096; }
  else if (t < 12288) { in = W3; out = B3; f = t - 8192; }
  else                { in = W4; out = B4; f = t - 12288; }
  int ln = f & 15, quad = (f >> 4) & 3, c = (f >> 6) & 7, ks = (f >> 9) & 3, hh = f >> 11;
  int n = c * 16 + ln;
  int k0 = hh * 128 + ks * 32 + quad * 8;
  union { u16 s[8]; uint4 q; } tmp;
#pragma unroll
  for (int j = 0; j < 8; ++j) tmp.s[j] = f2b(in[(size_t)(k0 + j) * 128 + n]);
  *(uint4*)(out + (size_t)f * 8) = tmp.q;
}

// ---------------- degree / CSR build ----------------
__global__ void k_count(const int* __restrict__ dst, int* __restrict__ cnt, int E) {
  int e = blockIdx.x * 256 + threadIdx.x; if (e < E) atomicAdd(&cnt[dst[e]], 1);
}

__global__ __launch_bounds__(256) void k_partial(const int* __restrict__ cnt,
                                                 int* __restrict__ bsum, int n) {
  int i = blockIdx.x * 256 + threadIdx.x;
  int v = (i < n) ? cnt[i] : 0;
  for (int off = 1; off < 64; off <<= 1) v += __shfl_down(v, off, 64);
  __shared__ int ws[4];
  int lane = threadIdx.x & 63, w = threadIdx.x >> 6;
  if (lane == 0) ws[w] = v;
  __syncthreads();
  if (threadIdx.x == 0) bsum[blockIdx.x] = ws[0] + ws[1] + ws[2] + ws[3];
}

__global__ void k_scanb(int* __restrict__ bsum, int nb) {
  __shared__ int sm[256];
  int tid = threadIdx.x;
  int v = (tid < nb) ? bsum[tid] : 0;
  sm[tid] = v; __syncthreads();
  int run = v;
  for (int off = 1; off < 256; off <<= 1) {
    int t = (tid >= off) ? sm[tid - off] : 0;
    __syncthreads();
    run += t; sm[tid] = run;
    __syncthreads();
  }
  if (tid < nb) bsum[tid] = run - v;   // exclusive block offsets
}

__global__ __launch_bounds__(256) void k_scatter(const int* __restrict__ cnt,
                                                 const int* __restrict__ bsum,
                                                 int* __restrict__ row_start,
                                                 int* __restrict__ cursor,
                                                 float* __restrict__ dinv, int n, int E) {
  int tid = threadIdx.x;
  int i = blockIdx.x * 256 + tid;
  int v = (i < n) ? cnt[i] : 0;
  int lane = tid & 63, w = tid >> 6;
  int run = v;
  for (int off = 1; off < 64; off <<= 1) {
    int t = __shfl_up(run, (unsigned)off, 64);
    if (lane >= off) run += t;
  }
  __shared__ int wsum[4];
  if (lane == 63) wsum[w] = run;
  __syncthreads();
  int woff = 0;
  for (int j = 0; j < w; ++j) woff += wsum[j];
  int excl = woff + run - v;
  if (i < n) {
    int rs = bsum[blockIdx.x] + excl;
    row_start[i] = rs; cursor[i] = rs;
    dinv[i] = rsqrtf((float)v + 1.0f);     // +1 self-loop
  }
  if (i == 0) row_start[n] = E;
}

__global__ void k_fill(const int* __restrict__ src, const int* __restrict__ dst,
                       int* __restrict__ cursor, int* __restrict__ csr_src, int E) {
  int e = blockIdx.x * 256 + threadIdx.x;
  if (e < E) { int p = atomicAdd(&cursor[dst[e]], 1); csr_src[p] = src[e]; }
}

// ---------------- aggregation: one wave per node ----------------
// indices fetched once (coalesced, lane-parallel), distributed by shfl;
// every row issues ceil(deg/8) groups of 8 concurrent gathers (predicated tail).
__global__ __launch_bounds__(256) void k_agg(const u16* __restrict__ y,
                                             const int* __restrict__ row_start,
                                             const int* __restrict__ csr_src,
                                             const float* __restrict__ dinv,
                                             const float* __restrict__ bias,
                                             u16* __restrict__ out, int relu, int N) {
  int wv = (blockIdx.x * 256 + threadIdx.x) >> 6;
  int lane = threadIdx.x & 63;
  if (wv >= N) return;
  const u32* yr = (const u32*)y;            // 2 bf16 per u32: feats 2*lane, 2*lane+1
  float di = dinv[wv];
  float bi0 = bias[lane * 2], bi1 = bias[lane * 2 + 1];
  u32 sv = yr[(size_t)wv * 64 + lane];
  float a0 = b2f((u16)(sv & 0xFFFF));
  float a1 = b2f((u16)(sv >> 16));
  int p0 = row_start[wv], p1 = row_start[wv + 1];
  int deg = p1 - p0;
  int degc = (deg < 64) ? deg : 64;
  int myidx = (lane < degc) ? csr_src[p0 + lane] : 0;
  int nb8 = (degc + 7) >> 3;
  for (int b = 0; b < nb8; ++b) {
    int base = b * 8;
    int s[8]; u32 v[8];
#pragma unroll
    for (int k = 0; k < 8; ++k) {
      int jj = base + k;
      s[k] = __shfl(myidx, (jj < degc) ? jj : 0, 64);
    }
#pragma unroll
    for (int k = 0; k < 8; ++k) v[k] = yr[(size_t)s[k] * 64 + lane];
#pragma unroll
    for (int k = 0; k < 8; ++k) {
      if (base + k < degc) {                // wave-uniform predicate
        a0 += b2f((u16)(v[k] & 0xFFFF));
        a1 += b2f((u16)(v[k] >> 16));
      }
    }
  }
  for (int p = p0 + 64; p < p1; ++p) {      // deg>64 never happens here; safety
    int s = csr_src[p];
    u32 v = yr[(size_t)s * 64 + lane];
    a0 += b2f((u16)(v & 0xFFFF));
    a1 += b2f((u16)(v >> 16));
  }
  float r0 = di * a0 + bi0;
  float r1 = di * a1 + bi1;
  if (relu) { r0 = fmaxf(r0, 0.0f); r1 = fmaxf(r1, 0.0f); }
  u32 o = (u32)f2b(r0) | ((u32)f2b(r1) << 16);
  ((u32*)out)[(size_t)wv * 64 + lane] = o;
}

// ---------------- layer GEMM: y[M,128] = bf16( (A[M,128] @ W) * dinv[row] ) ----------------
template <bool AF>   // A is fp32 (convert) or bf16
__global__ __launch_bounds__(256) void k_gemm(
    const void* __restrict__ Av,
    const u16* __restrict__ Bt,          // fragment-ordered, 16384 u16
    const float* __restrict__ rowscale,
    u16* __restrict__ outb, int M) {
  __shared__ __align__(16) u16 bs[16384];
  int tid = threadIdx.x;
  int lane = tid & 63, wave = tid >> 6;
  int ln = lane & 15, quad = lane >> 4;
  int rowbase = blockIdx.x * 64 + wave * 16;
  int rowA = rowbase + ln;
  long rA = (rowA < M) ? rowA : (M - 1);

  {
    const u16* g = Bt + wave * 4096 + lane * 8;
    u16* l = bs + wave * 4096;
#pragma unroll
    for (int i = 0; i < 8; ++i) ld_lds16(g + i * 512, l + i * 512);
  }

  bf8 af[4];
#pragma unroll
  for (int ks = 0; ks < 4; ++ks) {
    int kk = ks * 32 + quad * 8;
    if (AF) af[ks] = cvt8((const float*)Av + rA * 128 + kk);
    else    af[ks] = *(const bf8*)((const u16*)Av + rA * 128 + kk);
  }

  f32x4 acc[8];
#pragma unroll
  for (int c = 0; c < 8; ++c) { acc[c][0] = 0.f; acc[c][1] = 0.f; acc[c][2] = 0.f; acc[c][3] = 0.f; }

  __syncthreads();   // drains the async LDS DMA
#pragma unroll
  for (int ks = 0; ks < 4; ++ks) {
#pragma unroll
    for (int c = 0; c < 8; ++c) {
      bf8 bfr = *(const bf8*)(bs + ks * 4096 + c * 512 + lane * 8);
      acc[c] = __builtin_amdgcn_mfma_f32_16x16x32_bf16(af[ks], bfr, acc[c], 0, 0, 0);
    }
  }

  int rb = rowbase + quad * 4;
#pragma unroll
  for (int c = 0; c < 8; ++c) {
    int col = c * 16 + ln;
#pragma unroll
    for (int r = 0; r < 4; ++r) {
      int row = rb + r;
      if (row < M) outb[(size_t)row * 128 + col] = f2b(acc[c][r] * rowscale[row]);
    }
  }
}

// ---------------- fused GRU: out = (1-u)*h + u*tanh([emb | sig(r)*h] @ Wc + bc) ----------------
// 3 staging phases (z|r halves paired in one 64KB buffer), 5 barriers total.
__global__ __launch_bounds__(256) void k_gru(
    const u16* __restrict__ emb, const float* __restrict__ h,
    const u16* __restrict__ Btz, const u16* __restrict__ Btr, const u16* __restrict__ Btc,
    const float* __restrict__ bz, const float* __restrict__ br, const float* __restrict__ bc,
    float* __restrict__ out, int M) {
  __shared__ __align__(16) u16 bs[32768];   // 64 KB: two weight halves side by side
  __shared__ __align__(16) u16 at[8192];    // 16 KB: rh A-tile, stride 128
  int tid = threadIdx.x;
  int lane = tid & 63, wave = tid >> 6;
  int ln = lane & 15, quad = lane >> 4;
  int rowbase = blockIdx.x * 64 + wave * 16;
  int rowA = rowbase + ln;
  long rA = (rowA < M) ? rowA : (M - 1);
  int rb = rowbase + quad * 4;

  auto stage2 = [&](const u16* BtA, int hhA, const u16* BtB, int hhB) {
    const u16* gA = BtA + hhA * 16384 + wave * 4096 + lane * 8;
    const u16* gB = BtB + hhB * 16384 + wave * 4096 + lane * 8;
    u16* lA = bs + wave * 4096;
    u16* lB = bs + 16384 + wave * 4096;
#pragma unroll
    for (int i = 0; i < 8; ++i) { ld_lds16(gA + i * 512, lA + i * 512); }
#pragma unroll
    for (int i = 0; i < 8; ++i) { ld_lds16(gB + i * 512, lB + i * 512); }
  };
  auto mmpair = [&](const bf8 (&af)[4], f32x4 (&acc1)[8], f32x4 (&acc2)[8]) {
#pragma unroll
    for (int ks = 0; ks < 4; ++ks)
#pragma unroll
      for (int c = 0; c < 8; ++c) {
        bf8 b1 = *(const bf8*)(bs + ks * 4096 + c * 512 + lane * 8);
        acc1[c] = __builtin_amdgcn_mfma_f32_16x16x32_bf16(af[ks], b1, acc1[c], 0, 0, 0);
        bf8 b2 = *(const bf8*)(bs + 16384 + ks * 4096 + c * 512 + lane * 8);
        acc2[c] = __builtin_amdgcn_mfma_f32_16x16x32_bf16(af[ks], b2, acc2[c], 0, 0, 0);
      }
  };

  // phase 1 DMA first; overlap register preloads under it
  stage2(Btz, 0, Btr, 0);

  bf8 af_e[4], af_h[4];
#pragma unroll
  for (int ks = 0; ks < 4; ++ks)
    af_e[ks] = *(const bf8*)(emb + rA * 128 + ks * 32 + quad * 8);
#pragma unroll
  for (int ks = 0; ks < 4; ++ks)
    af_h[ks] = cvt8(h + rA * 128 + ks * 32 + quad * 8);

  f32x4 hc[8];
#pragma unroll
  for (int c = 0; c < 8; ++c) {
    int col = c * 16 + ln;
#pragma unroll
    for (int r = 0; r < 4; ++r) {
      int row = rb + r;
      hc[c][r] = (row < M) ? h[(size_t)row * 128 + col] : 0.0f;
    }
  }

  f32x4 accz[8], accr[8];
#pragma unroll
  for (int c = 0; c < 8; ++c) {
    accz[c][0] = 0.f; accz[c][1] = 0.f; accz[c][2] = 0.f; accz[c][3] = 0.f;
    accr[c][0] = 0.f; accr[c][1] = 0.f; accr[c][2] = 0.f; accr[c][3] = 0.f;
  }

  __syncthreads();                       // B1: z0|r0 staged
  mmpair(af_e, accz, accr);
  __syncthreads();                       // B2: WAR before restage
  stage2(Btz, 1, Btr, 1);
  __syncthreads();                       // B3: z1|r1 staged
  mmpair(af_h, accz, accr);

  // u = sigmoid(accz+bz); rh = sigmoid(accr+br)*h -> at (A-layout source tile)
#pragma unroll
  for (int c = 0; c < 8; ++c) {
    int col = c * 16 + ln;
    float bzc = bz[col], brc = br[col];
#pragma unroll
    for (int r = 0; r < 4; ++r) {
      float uu = sigf(accz[c][r] + bzc);
      float rr = sigf(accr[c][r] + brc);
      accz[c][r] = uu;                       // keep u in registers
      int lrow = wave * 16 + quad * 4 + r;   // local block row
      at[lrow * 128 + col] = f2b(rr * hc[c][r]);
      accr[c][r] = 0.0f;                     // accr becomes candidate accumulator
    }
  }
  __syncthreads();                       // B4: at visible + WAR for phase-3 stage
  stage2(Btc, 0, Btc, 1);
  bf8 af_at[4];                          // ds_read overlapped under phase-3 DMA
#pragma unroll
  for (int ks = 0; ks < 4; ++ks)
    af_at[ks] = *(const bf8*)(at + (wave * 16 + ln) * 128 + ks * 32 + quad * 8);
  __syncthreads();                       // B5: c0|c1 staged
#pragma unroll
  for (int ks = 0; ks < 4; ++ks)
#pragma unroll
    for (int c = 0; c < 8; ++c) {
      bf8 b1 = *(const bf8*)(bs + ks * 4096 + c * 512 + lane * 8);
      accr[c] = __builtin_amdgcn_mfma_f32_16x16x32_bf16(af_e[ks], b1, accr[c], 0, 0, 0);
      bf8 b2 = *(const bf8*)(bs + 16384 + ks * 4096 + c * 512 + lane * 8);
      accr[c] = __builtin_amdgcn_mfma_f32_16x16x32_bf16(af_at[ks], b2, accr[c], 0, 0, 0);
    }

  // epilogue: out = (1-u)*h + u*tanh(accc + bc)
#pragma unroll
  for (int c = 0; c < 8; ++c) {
    int col = c * 16 + ln;
    float bcc = bc[col];
#pragma unroll
    for (int r = 0; r < 4; ++r) {
      int row = rb + r;
      if (row < M) {
        float cd = tanhfast(accr[c][r] + bcc);
        float uu = accz[c][r];
        out[(size_t)row * 128 + col] = (1.0f - uu) * hc[c][r] + uu * cd;
      }
    }
  }
}

extern "C" void kernel_launch(void* const* d_in, const int* in_sizes, int n_in,
                              void* d_out, int out_size, void* d_ws, size_t ws_size,
                              hipStream_t stream) {
  const float* x     = (const float*)d_in[0];
  const float* h     = (const float*)d_in[1];
  const int*   ei    = (const int*)d_in[2];
  const float* W_in  = (const float*)d_in[3];
  const float* b_in  = (const float*)d_in[4];
  const float* W_hid = (const float*)d_in[5];
  const float* b_hid = (const float*)d_in[6];
  const float* W_z   = (const float*)d_in[7];
  const float* b_z   = (const float*)d_in[8];
  const float* W_r   = (const float*)d_in[9];
  const float* b_r   = (const float*)d_in[10];
  const float* W_c   = (const float*)d_in[11];
  const float* b_c   = (const float*)d_in[12];

  const int N = in_sizes[0] / 128;
  const int E = in_sizes[2] / 2;
  const int* src = ei;
  const int* dst = ei + E;

  char* p = (char*)d_ws;
  auto carve = [&](size_t bytes) { char* r = p; p += (bytes + 255) & ~(size_t)255; return r; };
  u16* Bt_in   = (u16*)carve((size_t)16384 * 2);
  u16* Bt_hid  = (u16*)carve((size_t)16384 * 2);
  u16* Bt_z    = (u16*)carve((size_t)32768 * 2);
  u16* Bt_r    = (u16*)carve((size_t)32768 * 2);
  u16* Bt_c    = (u16*)carve((size_t)32768 * 2);
  int* cnt       = (int*)carve((size_t)N * 4);
  int* row_start = (int*)carve((size_t)(N + 1) * 4);
  int* cursor    = (int*)carve((size_t)N * 4);
  int* bsum      = (int*)carve(1024);
  int* csr       = (int*)carve((size_t)E * 4);
  float* dinv    = (float*)carve((size_t)N * 4);
  u16* y    = (u16*)carve((size_t)N * 128 * 2);    // bf16 intermediates
  u16* h1   = (u16*)carve((size_t)N * 128 * 2);
  u16* emb  = (u16*)carve((size_t)N * 128 * 2);

  int gN = (N + 255) / 256;
  int gE = (E + 255) / 256;
  int nb = gN;                 // partial-sum blocks (<=256; 196 here)
  int gG = (N + 63) / 64;      // GEMM/GRU: 64 rows per block
  int gA = (N + 3) / 4;        // AGG: 4 waves (nodes) per block

  k_transpose<<<64 + gN, 256, 0, stream>>>(W_in, W_hid, W_z, W_r, W_c,
                                           Bt_in, Bt_hid, Bt_z, Bt_r, Bt_c, cnt, N);
  k_count<<<gE, 256, 0, stream>>>(dst, cnt, E);
  k_partial<<<nb, 256, 0, stream>>>(cnt, bsum, N);
  k_scanb<<<1, 256, 0, stream>>>(bsum, nb);
  k_scatter<<<nb, 256, 0, stream>>>(cnt, bsum, row_start, cursor, dinv, N, E);
  k_fill<<<gE, 256, 0, stream>>>(src, dst, cursor, csr, E);

  // layer 1: y = (x @ W_in) * dinv ; h1 = relu(dinv * agg(y) + b_in)
  k_gemm<true><<<gG, 256, 0, stream>>>(x, Bt_in, dinv, y, N);
  k_agg<<<gA, 256, 0, stream>>>(y, row_start, csr, dinv, b_in, h1, 1, N);
  // layer 2: y = (h1 @ W_hid) * dinv ; emb = dinv * agg(y) + b_hid
  k_gemm<false><<<gG, 256, 0, stream>>>(h1, Bt_hid, dinv, y, N);
  k_agg<<<gA, 256, 0, stream>>>(y, row_start, csr, dinv, b_hid, emb, 0, N);
  // fused GRU
  k_gru<<<gG, 256, 0, stream>>>(emb, h, Bt_z, Bt_r, Bt_c, b_z, b_r, b_c, (float*)d_out, N);
}

// Round 6
// 268.874 us; speedup vs baseline: 1.5020x; 1.1088x over previous
//
#include <hip/hip_runtime.h>
#include <cstdint>
#include <cstddef>

typedef unsigned short u16;
typedef unsigned int   u32;

typedef __bf16 bf8   __attribute__((ext_vector_type(8)));
typedef float  f32x4 __attribute__((ext_vector_type(4)));

__device__ __forceinline__ float b2f(u16 v) {
  union { u32 i; float f; } c; c.i = ((u32)v) << 16; return c.f;
}
__device__ __forceinline__ u16 f2b(float f) {
  union { u32 i; float f; } c; c.f = f;
  u32 x = c.i;
  u32 r = (x + 0x7FFFu + ((x >> 16) & 1u)) >> 16;
  return (u16)r;
}
__device__ __forceinline__ float sigf(float x) { return 1.0f / (1.0f + __expf(-x)); }
__device__ __forceinline__ float tanhfast(float x) { return 2.0f * sigf(2.0f * x) - 1.0f; }

// convert 8 consecutive floats to a bf16x8 fragment (RNE)
__device__ __forceinline__ bf8 cvt8(const float* __restrict__ p) {
  f32x4 lo = *(const f32x4*)p;
  f32x4 hi = *(const f32x4*)(p + 4);
  union { u16 s[8]; bf8 v; } c;
#pragma unroll
  for (int i = 0; i < 4; ++i) { c.s[i] = f2b(lo[i]); c.s[4 + i] = f2b(hi[i]); }
  return c.v;
}
__device__ __forceinline__ bf8 asbf8(uint4 q) {
  union { uint4 q; bf8 v; } c; c.q = q; return c.v;
}

// async 16B global -> LDS (dest = wave-uniform base + lane*16)
__device__ __forceinline__ void ld_lds16(const u16* g, u16* l) {
  __builtin_amdgcn_global_load_lds((const __attribute__((address_space(1))) void*)g,
                                   (__attribute__((address_space(3))) void*)l, 16, 0, 0);
}

#define CSR_STRIDE 80

// ---- weight repack: W fp32 [K x 128] -> Bt bf16 in MFMA-fragment order ----
// frag id f = (hh*4+ks)*512 + c*64 + lane ; element j in [0,8):
//   Bt[f*8+j] = bf16( W[(hh*128+ks*32+quad*8+j)*128 + (c*16+ln)] )   (lane=quad*16+ln)
// blocks >= 64 zero the degree-count array instead.
__global__ __launch_bounds__(256) void k_transpose(
    const float* __restrict__ W0, const float* __restrict__ W1,
    const float* __restrict__ W2, const float* __restrict__ W3,
    const float* __restrict__ W4,
    u16* __restrict__ B0, u16* __restrict__ B1, u16* __restrict__ B2,
    u16* __restrict__ B3, u16* __restrict__ B4,
    int* __restrict__ cnt, int N) {
  if (blockIdx.x >= 64) {
    int i = (blockIdx.x - 64) * 256 + threadIdx.x;
    if (i < N) cnt[i] = 0;
    return;
  }
  int t = blockIdx.x * 256 + threadIdx.x;
  const float* in; u16* out; int f;
  if (t < 2048)       { in = W0; out = B0; f = t; }
  else if (t < 4096)  { in = W1; out = B1; f = t - 2048; }
  else if (t < 8192)  { in = W2; out = B2; f = t - 4096; }
  else if (t < 12288) { in = W3; out = B3; f = t - 8192; }
  else                { in = W4; out = B4; f = t - 12288; }
  int ln = f & 15, quad = (f >> 4) & 3, c = (f >> 6) & 7, ks = (f >> 9) & 3, hh = f >> 11;
  int n = c * 16 + ln;
  int k0 = hh * 128 + ks * 32 + quad * 8;
  union { u16 s[8]; uint4 q; } tmp;
#pragma unroll
  for (int j = 0; j < 8; ++j) tmp.s[j] = f2b(in[(size_t)(k0 + j) * 128 + n]);
  *(uint4*)(out + (size_t)f * 8) = tmp.q;
}

// ---------------- CSR build: one pass; cnt doubles as cursor and final degree ----------------
__global__ void k_fill(const int* __restrict__ src, const int* __restrict__ dst,
                       int* __restrict__ cnt, int* __restrict__ csr, int E) {
  int e = blockIdx.x * 256 + threadIdx.x;
  if (e < E) {
    int d = dst[e];
    int pos = atomicAdd(&cnt[d], 1);
    if (pos < CSR_STRIDE) csr[(size_t)d * CSR_STRIDE + pos] = src[e];
  }
}

// ---------------- aggregation: one wave per node, 4 edges x 16-lane x 16B ----------------
// out[d] = postproc( rsqrt(deg+1) * (sum_{s->d} y[s] + y[d]) + bias )
__global__ __launch_bounds__(256) void k_agg(const u16* __restrict__ y,
                                             const int* __restrict__ cnt,
                                             const int* __restrict__ csr,
                                             const float* __restrict__ bias,
                                             u16* __restrict__ out, int relu, int N) {
  int wv = (blockIdx.x * 256 + threadIdx.x) >> 6;
  int lane = threadIdx.x & 63;
  if (wv >= N) return;
  int g = lane >> 4, t = lane & 15;
  const uint4* yq = (const uint4*)y;        // 16 uint4 per 128-feat bf16 row
  int deg = cnt[wv];
  int degc = (deg < 64) ? deg : 64;
  long base = (long)wv * CSR_STRIDE;
  int myidx = (lane < degc) ? csr[base + lane] : 0;

  float a[8];
#pragma unroll
  for (int j = 0; j < 8; ++j) a[j] = 0.0f;

  for (int b = 0; b < degc; b += 8) {
    int e0 = b + g, e1 = b + 4 + g;
    int s0 = __shfl(myidx, (e0 < degc) ? e0 : 0, 64);
    int s1 = __shfl(myidx, (e1 < degc) ? e1 : 0, 64);
    uint4 v0 = yq[(size_t)s0 * 16 + t];
    uint4 v1 = yq[(size_t)s1 * 16 + t];
    if (e0 < degc) {
      const u32* w = (const u32*)&v0;
#pragma unroll
      for (int i = 0; i < 4; ++i) { a[2*i] += b2f((u16)(w[i] & 0xFFFF)); a[2*i+1] += b2f((u16)(w[i] >> 16)); }
    }
    if (e1 < degc) {
      const u32* w = (const u32*)&v1;
#pragma unroll
      for (int i = 0; i < 4; ++i) { a[2*i] += b2f((u16)(w[i] & 0xFFFF)); a[2*i+1] += b2f((u16)(w[i] >> 16)); }
    }
  }
  // cross-group reduction: groups 0..3 hold partial sums of the same feature slice
#pragma unroll
  for (int j = 0; j < 8; ++j) {
    a[j] += __shfl_xor(a[j], 16, 64);
    a[j] += __shfl_xor(a[j], 32, 64);
  }
  if (g == 0) {
    // rare tail deg in (64, 80): add serially (16 lanes do full rows)
    int degt = (deg < CSR_STRIDE) ? deg : CSR_STRIDE;
    for (int p = 64; p < degt; ++p) {
      int s = csr[base + p];
      uint4 v = yq[(size_t)s * 16 + t];
      const u32* w = (const u32*)&v;
#pragma unroll
      for (int i = 0; i < 4; ++i) { a[2*i] += b2f((u16)(w[i] & 0xFFFF)); a[2*i+1] += b2f((u16)(w[i] >> 16)); }
    }
    // self-loop
    uint4 sv = yq[(size_t)wv * 16 + t];
    const u32* w = (const u32*)&sv;
#pragma unroll
    for (int i = 0; i < 4; ++i) { a[2*i] += b2f((u16)(w[i] & 0xFFFF)); a[2*i+1] += b2f((u16)(w[i] >> 16)); }
    float di = rsqrtf((float)deg + 1.0f);
    f32x4 b0 = *(const f32x4*)(bias + t * 8);
    f32x4 b1 = *(const f32x4*)(bias + t * 8 + 4);
    union { u16 s[8]; uint4 q; } o;
#pragma unroll
    for (int j = 0; j < 8; ++j) {
      float r = di * a[j] + ((j < 4) ? b0[j] : b1[j - 4]);
      if (relu) r = fmaxf(r, 0.0f);
      o.s[j] = f2b(r);
    }
    ((uint4*)out)[(size_t)wv * 16 + t] = o.q;
  }
}

// ---------------- layer GEMM: y[M,128] = bf16( (A[M,128] @ W) * rsqrt(deg+1)[row] ) ----------------
template <bool AF>   // A is fp32 (convert) or bf16
__global__ __launch_bounds__(256) void k_gemm(
    const void* __restrict__ Av,
    const u16* __restrict__ Bt,          // fragment-ordered, 16384 u16
    const int* __restrict__ cnt,
    u16* __restrict__ outb, int M) {
  __shared__ __align__(16) u16 bs[16384];
  int tid = threadIdx.x;
  int lane = tid & 63, wave = tid >> 6;
  int ln = lane & 15, quad = lane >> 4;
  int rowbase = blockIdx.x * 64 + wave * 16;
  int rowA = rowbase + ln;
  long rA = (rowA < M) ? rowA : (M - 1);

  {
    const u16* g = Bt + wave * 4096 + lane * 8;
    u16* l = bs + wave * 4096;
#pragma unroll
    for (int i = 0; i < 8; ++i) ld_lds16(g + i * 512, l + i * 512);
  }

  bf8 af[4];
#pragma unroll
  for (int ks = 0; ks < 4; ++ks) {
    int kk = ks * 32 + quad * 8;
    if (AF) af[ks] = cvt8((const float*)Av + rA * 128 + kk);
    else    af[ks] = *(const bf8*)((const u16*)Av + rA * 128 + kk);
  }

  f32x4 acc[8];
#pragma unroll
  for (int c = 0; c < 8; ++c) { acc[c][0] = 0.f; acc[c][1] = 0.f; acc[c][2] = 0.f; acc[c][3] = 0.f; }

  __syncthreads();   // drains the async LDS DMA
#pragma unroll
  for (int ks = 0; ks < 4; ++ks) {
#pragma unroll
    for (int c = 0; c < 8; ++c) {
      bf8 bfr = *(const bf8*)(bs + ks * 4096 + c * 512 + lane * 8);
      acc[c] = __builtin_amdgcn_mfma_f32_16x16x32_bf16(af[ks], bfr, acc[c], 0, 0, 0);
    }
  }

  int rb = rowbase + quad * 4;
  float rs[4];
#pragma unroll
  for (int r = 0; r < 4; ++r) {
    int row = rb + r;
    rs[r] = (row < M) ? rsqrtf((float)cnt[row] + 1.0f) : 0.0f;
  }
#pragma unroll
  for (int c = 0; c < 8; ++c) {
    int col = c * 16 + ln;
#pragma unroll
    for (int r = 0; r < 4; ++r) {
      int row = rb + r;
      if (row < M) outb[(size_t)row * 128 + col] = f2b(acc[c][r] * rs[r]);
    }
  }
}

// ---------------- fused GRU, global-streamed weights, 1 barrier ----------------
// out = (1-u)*h + u*tanh([emb | sig(r)*h] @ Wc + bc); u = sig([emb|h]@Wz+bz)
__global__ __launch_bounds__(256, 2) void k_gru(
    const u16* __restrict__ emb, const float* __restrict__ h,
    const u16* __restrict__ Btz, const u16* __restrict__ Btr, const u16* __restrict__ Btc,
    const float* __restrict__ bz, const float* __restrict__ br, const float* __restrict__ bc,
    float* __restrict__ out, int M) {
  __shared__ __align__(16) u16 at[8192];    // 16 KB rh A-tile, stride 128
  int tid = threadIdx.x;
  int lane = tid & 63, wave = tid >> 6;
  int ln = lane & 15, quad = lane >> 4;
  int rowbase = blockIdx.x * 64 + wave * 16;
  int rowA = rowbase + ln;
  long rA = (rowA < M) ? rowA : (M - 1);
  int rb = rowbase + quad * 4;

  const uint4* Bz = (const uint4*)Btz;
  const uint4* Br = (const uint4*)Btr;
  const uint4* Bc = (const uint4*)Btc;

  // A fragments (registers, reused across all three GEMMs)
  bf8 af_e[4], af_h[4];
#pragma unroll
  for (int ks = 0; ks < 4; ++ks)
    af_e[ks] = *(const bf8*)(emb + rA * 128 + ks * 32 + quad * 8);
#pragma unroll
  for (int ks = 0; ks < 4; ++ks)
    af_h[ks] = cvt8(h + rA * 128 + ks * 32 + quad * 8);

  f32x4 accz[8], accr[8];
#pragma unroll
  for (int c = 0; c < 8; ++c) {
    accz[c][0] = 0.f; accz[c][1] = 0.f; accz[c][2] = 0.f; accz[c][3] = 0.f;
    accr[c][0] = 0.f; accr[c][1] = 0.f; accr[c][2] = 0.f; accr[c][3] = 0.f;
  }

  auto loadb = [&](uint4 (&d)[8], const uint4* B, int ksg) {
#pragma unroll
    for (int c = 0; c < 8; ++c) d[c] = B[(size_t)ksg * 512 + c * 64 + lane];
  };
  auto mmzr = [&](uint4 (&cz)[8], uint4 (&cr)[8], int ksg) {
    bf8 af = (ksg < 4) ? af_e[ksg] : af_h[ksg - 4];
#pragma unroll
    for (int c = 0; c < 8; ++c) {
      accz[c] = __builtin_amdgcn_mfma_f32_16x16x32_bf16(af, asbf8(cz[c]), accz[c], 0, 0, 0);
      accr[c] = __builtin_amdgcn_mfma_f32_16x16x32_bf16(af, asbf8(cr[c]), accr[c], 0, 0, 0);
    }
  };

  // z/r pass: ping-pong prefetch, MFMA interleaved with in-flight loads
  uint4 z0[8], r0[8], z1[8], r1[8];
  loadb(z0, Bz, 0); loadb(r0, Br, 0);
  loadb(z1, Bz, 1); loadb(r1, Br, 1);
  mmzr(z0, r0, 0);
  loadb(z0, Bz, 2); loadb(r0, Br, 2);
  mmzr(z1, r1, 1);
  loadb(z1, Bz, 3); loadb(r1, Br, 3);
  mmzr(z0, r0, 2);
  loadb(z0, Bz, 4); loadb(r0, Br, 4);
  mmzr(z1, r1, 3);
  loadb(z1, Bz, 5); loadb(r1, Br, 5);
  mmzr(z0, r0, 4);
  loadb(z0, Bz, 6); loadb(r0, Br, 6);
  mmzr(z1, r1, 5);
  loadb(z1, Bz, 7); loadb(r1, Br, 7);
  mmzr(z0, r0, 6);
  mmzr(z1, r1, 7);

  // h at C-layout positions (for rh and final blend)
  f32x4 hc[8];
#pragma unroll
  for (int c = 0; c < 8; ++c) {
    int col = c * 16 + ln;
#pragma unroll
    for (int r = 0; r < 4; ++r) {
      int row = rb + r;
      hc[c][r] = (row < M) ? h[(size_t)row * 128 + col] : 0.0f;
    }
  }

  // u = sigmoid(accz+bz); rh = sigmoid(accr+br)*h -> at (A-source tile)
#pragma unroll
  for (int c = 0; c < 8; ++c) {
    int col = c * 16 + ln;
    float bzc = bz[col], brc = br[col];
#pragma unroll
    for (int r = 0; r < 4; ++r) {
      float uu = sigf(accz[c][r] + bzc);
      float rr = sigf(accr[c][r] + brc);
      accz[c][r] = uu;                       // keep u in registers
      int lrow = wave * 16 + quad * 4 + r;   // local block row
      at[lrow * 128 + col] = f2b(rr * hc[c][r]);
      accr[c][r] = 0.0f;                     // accr becomes candidate accumulator
    }
  }
  __syncthreads();                           // the ONLY barrier: at visible

  bf8 af_at[4];
#pragma unroll
  for (int ks = 0; ks < 4; ++ks)
    af_at[ks] = *(const bf8*)(at + (wave * 16 + ln) * 128 + ks * 32 + quad * 8);

  auto mmc = [&](uint4 (&cc)[8], int ksg) {
    bf8 af = (ksg < 4) ? af_e[ksg] : af_at[ksg - 4];
#pragma unroll
    for (int c = 0; c < 8; ++c)
      accr[c] = __builtin_amdgcn_mfma_f32_16x16x32_bf16(af, asbf8(cc[c]), accr[c], 0, 0, 0);
  };
  uint4 c0[8], c1[8];
  loadb(c0, Bc, 0);
  loadb(c1, Bc, 1);
  mmc(c0, 0);
  loadb(c0, Bc, 2);
  mmc(c1, 1);
  loadb(c1, Bc, 3);
  mmc(c0, 2);
  loadb(c0, Bc, 4);
  mmc(c1, 3);
  loadb(c1, Bc, 5);
  mmc(c0, 4);
  loadb(c0, Bc, 6);
  mmc(c1, 5);
  loadb(c1, Bc, 7);
  mmc(c0, 6);
  mmc(c1, 7);

  // epilogue: out = (1-u)*h + u*tanh(accc + bc)
#pragma unroll
  for (int c = 0; c < 8; ++c) {
    int col = c * 16 + ln;
    float bcc = bc[col];
#pragma unroll
    for (int r = 0; r < 4; ++r) {
      int row = rb + r;
      if (row < M) {
        float cd = tanhfast(accr[c][r] + bcc);
        float uu = accz[c][r];
        out[(size_t)row * 128 + col] = (1.0f - uu) * hc[c][r] + uu * cd;
      }
    }
  }
}

extern "C" void kernel_launch(void* const* d_in, const int* in_sizes, int n_in,
                              void* d_out, int out_size, void* d_ws, size_t ws_size,
                              hipStream_t stream) {
  const float* x     = (const float*)d_in[0];
  const float* h     = (const float*)d_in[1];
  const int*   ei    = (const int*)d_in[2];
  const float* W_in  = (const float*)d_in[3];
  const float* b_in  = (const float*)d_in[4];
  const float* W_hid = (const float*)d_in[5];
  const float* b_hid = (const float*)d_in[6];
  const float* W_z   = (const float*)d_in[7];
  const float* b_z   = (const float*)d_in[8];
  const float* W_r   = (const float*)d_in[9];
  const float* b_r   = (const float*)d_in[10];
  const float* W_c   = (const float*)d_in[11];
  const float* b_c   = (const float*)d_in[12];

  const int N = in_sizes[0] / 128;
  const int E = in_sizes[2] / 2;
  const int* src = ei;
  const int* dst = ei + E;

  char* p = (char*)d_ws;
  auto carve = [&](size_t bytes) { char* r = p; p += (bytes + 255) & ~(size_t)255; return r; };
  u16* Bt_in   = (u16*)carve((size_t)16384 * 2);
  u16* Bt_hid  = (u16*)carve((size_t)16384 * 2);
  u16* Bt_z    = (u16*)carve((size_t)32768 * 2);
  u16* Bt_r    = (u16*)carve((size_t)32768 * 2);
  u16* Bt_c    = (u16*)carve((size_t)32768 * 2);
  int* cnt  = (int*)carve((size_t)N * 4);
  int* csr  = (int*)carve((size_t)N * CSR_STRIDE * 4);
  u16* y    = (u16*)carve((size_t)N * 128 * 2);    // bf16 intermediates
  u16* h1   = (u16*)carve((size_t)N * 128 * 2);
  u16* emb  = (u16*)carve((size_t)N * 128 * 2);

  int gN = (N + 255) / 256;
  int gE = (E + 255) / 256;
  int gG = (N + 63) / 64;      // GEMM/GRU: 64 rows per block
  int gA = (N + 3) / 4;        // AGG: 4 waves (nodes) per block

  k_transpose<<<64 + gN, 256, 0, stream>>>(W_in, W_hid, W_z, W_r, W_c,
                                           Bt_in, Bt_hid, Bt_z, Bt_r, Bt_c, cnt, N);
  k_fill<<<gE, 256, 0, stream>>>(src, dst, cnt, csr, E);

  // layer 1: y = (x @ W_in) * dinv ; h1 = relu(dinv * agg(y) + b_in)
  k_gemm<true><<<gG, 256, 0, stream>>>(x, Bt_in, cnt, y, N);
  k_agg<<<gA, 256, 0, stream>>>(y, cnt, csr, b_in, h1, 1, N);
  // layer 2: y = (h1 @ W_hid) * dinv ; emb = dinv * agg(y) + b_hid
  k_gemm<false><<<gG, 256, 0, stream>>>(h1, Bt_hid, cnt, y, N);
  k_agg<<<gA, 256, 0, stream>>>(y, cnt, csr, b_hid, emb, 0, N);
  // fused GRU
  k_gru<<<gG, 256, 0, stream>>>(emb, h, Bt_z, Bt_r, Bt_c, b_z, b_r, b_c, (float*)d_out, N);
}